// Round 8
// baseline (628.264 us; speedup 1.0000x reference)
//
#include <hip/hip_runtime.h>
#include <math.h>

typedef short s16;
typedef __attribute__((ext_vector_type(8))) short short8;
typedef __attribute__((ext_vector_type(4))) float f32x4;

__device__ __forceinline__ float bf2f_lo(unsigned u){ return __builtin_bit_cast(float, u << 16); }
__device__ __forceinline__ float bf2f_hi(unsigned u){ return __builtin_bit_cast(float, u & 0xffff0000u); }
__device__ __forceinline__ float bf2f(unsigned short h){ return __builtin_bit_cast(float, (unsigned)h << 16); }
__device__ __forceinline__ s16 f2bf(float f){
  unsigned u = __builtin_bit_cast(unsigned, f);
  u += 0x7fffu + ((u >> 16) & 1u);
  return (s16)(u >> 16);
}
__device__ __forceinline__ void unpack8(int4 v, float* f){
  unsigned a=(unsigned)v.x, b=(unsigned)v.y, c=(unsigned)v.z, d=(unsigned)v.w;
  f[0]=bf2f_lo(a); f[1]=bf2f_hi(a); f[2]=bf2f_lo(b); f[3]=bf2f_hi(b);
  f[4]=bf2f_lo(c); f[5]=bf2f_hi(c); f[6]=bf2f_lo(d); f[7]=bf2f_hi(d);
}
// async global->LDS 16B: lds dest is wave-uniform base + lane*16.
// r5 lesson: NEVER use the builtin's imm offset (corrupts on gfx950) —
// pass 0 and fold all K-advance into the pointer.
__device__ __forceinline__ void gl2lds16(const s16* g, s16* l){
  __builtin_amdgcn_global_load_lds((const __attribute__((address_space(1))) void*)g,
                                   (__attribute__((address_space(3))) void*)l, 16, 0, 0);
}

// ---------------- LayerNorm (fp32 in) -> bf16 out, D=1024, 1 block/row ------
__global__ __launch_bounds__(256) void ln_bf16(const float* __restrict__ x,
                                               const float* __restrict__ w,
                                               const float* __restrict__ b,
                                               s16* __restrict__ out){
  int row = blockIdx.x; int t = threadIdx.x;
  const float* xr = x + (size_t)row * 1024;
  float4 v = *(const float4*)(xr + t*4);
  float s = v.x + v.y + v.z + v.w;
  float ss = v.x*v.x + v.y*v.y + v.z*v.z + v.w*v.w;
  for (int o = 32; o > 0; o >>= 1){ s += __shfl_down(s, o, 64); ss += __shfl_down(ss, o, 64); }
  __shared__ float red[8];
  int wid = t >> 6, lane = t & 63;
  if (lane == 0){ red[wid] = s; red[4+wid] = ss; }
  __syncthreads();
  if (t == 0){
    float S = red[0]+red[1]+red[2]+red[3];
    float SS = red[4]+red[5]+red[6]+red[7];
    red[0] = S * (1.f/1024.f);
    red[1] = SS * (1.f/1024.f);
  }
  __syncthreads();
  float mu = red[0];
  float var = red[1] - mu*mu;
  float rstd = rsqrtf(var + 1e-6f);
  float vv[4] = {v.x, v.y, v.z, v.w};
  short4 o4;
  s16 tmp[4];
  #pragma unroll
  for (int i = 0; i < 4; ++i){
    int c = t*4 + i;
    float val = (vv[i] - mu) * rstd * w[c] + b[c];
    tmp[i] = f2bf(val);
  }
  o4.x = tmp[0]; o4.y = tmp[1]; o4.z = tmp[2]; o4.w = tmp[3];
  *(short4*)(out + (size_t)row*1024 + t*4) = o4;
}

// ---------------- transpose-convert fp32 W[K,N] -> bf16 Wt[N,K], with scale --
__global__ __launch_bounds__(256) void conv_t(const float* __restrict__ W,
                                              s16* __restrict__ Wt,
                                              int K, int N, float scale){
  __shared__ float tile[32][33];
  int n0 = blockIdx.x * 32, k0 = blockIdx.y * 32;
  int tx = threadIdx.x & 31, ty = threadIdx.x >> 5;   // ty 0..7
  #pragma unroll
  for (int i = 0; i < 4; ++i){
    int r = ty + i*8;
    tile[r][tx] = W[(size_t)(k0 + r)*N + n0 + tx];
  }
  __syncthreads();
  #pragma unroll
  for (int i = 0; i < 4; ++i){
    int r = ty + i*8;
    Wt[(size_t)(n0 + r)*K + k0 + tx] = f2bf(tile[tx][r] * scale);
  }
}

// XCD swizzle: 1D grid, tiles_y M-tiles (divisible by 8). Each XCD owns a
// disjoint M-row stripe (A fetched once, per-XCD L2); N iterated slowly so
// the B-slab stays hot across sy consecutive on-XCD blocks.
__device__ __forceinline__ void xcd_tile(int tiles_y, int& tx, int& ty){
  int id = blockIdx.x;
  int sy = tiles_y >> 3;
  int xcd = id & 7, p = id >> 3;
  ty = xcd * sy + (p % sy);
  tx = p / sy;
}

#define VMW(n) asm volatile("s_waitcnt vmcnt(" #n ")" ::: "memory")
#define BARR() asm volatile("s_barrier" ::: "memory")
#define LGKM0() asm volatile("s_waitcnt lgkmcnt(0)" ::: "memory")

// ============ 256x256 bf16 GEMM — faithful m201 phase template ==============
// Per phase: {ds_read THIS phase's frags; stage 1 half-tile; BARR; lgkm0;
// setprio1; 16 MFMA; setprio0; BARR}. 8 barriers/tile. Reads of all 8 waves
// are issued before any wave's MFMA -> LDS queue drains under barrier wait +
// other waves' MFMA. Slot recycle airtight: a slot's readers all pass the
// pre-MFMA barrier (reads complete via lgkm0) before any wave reaches the
// next phase's stage of that slot.
// Phases (tile t, cur buf c, nxt n): P1 rd{A0,B0} stg A1(t+1)->n.A1;
// P2 rd{B1} stg A0(t+2)->c.A0; P3 rd{A1->af} stg B0(t+2)->c.B0;
// P4 rd{} stg B1(t+2)->c.B1, VMW(6).
// vmcnt: 6 outstanding at tile start, +8/tile, VMW(6)@P4 retires tile t+1.
// Frags: single af (A0 for P1/P2, overwritten with A1 at P3) + bf0 + bf1.
// Addressing: x2-unrolled (literal buf), 8 persistent global ptrs +64/use
// (offset 0, r5), LDS reads off precomputed bases + literal offsets.
// Swizzle: phys c8 = c8 ^ (row&7), pre-swizzled global source; 0 conflicts.
__global__ __launch_bounds__(512,2) void gemm256(const s16* __restrict__ A,
                                                 const s16* __restrict__ Bt,
                                                 int N, int K,
                                                 s16* __restrict__ Cb,
                                                 const float* __restrict__ bias,
                                                 int flags, int tiles_y){
  __shared__ s16 lds[2*4*8192];   // [buf][slot: A0,A1,B0,B1][128*64]
  int t = threadIdx.x;
  int tx, ty; xcd_tile(tiles_y, tx, ty);
  int m0 = ty * 256, n0 = tx * 256;
  int w = t >> 6, lane = t & 63;
  int wm = w >> 2, wn = w & 3;         // 2M x 4N
  int lrow = lane & 15, lq = lane >> 4;
  int s = lrow & 7;

  int grow = t >> 3;                   // 0..63
  int g = (t & 7) ^ (grow & 7);
  int wo = w * 512;                    // wave dest offset (elems) in 8KB round

  const s16* pA0 = A  + (size_t)(m0 + grow) * K + g*8;
  const s16* pA1 = pA0 + (size_t)64*K;
  const s16* pA2 = pA0 + (size_t)128*K;
  const s16* pA3 = pA0 + (size_t)192*K;
  const s16* pB0 = Bt + (size_t)(n0 + grow) * K + g*8;
  const s16* pB1 = pB0 + (size_t)64*K;
  const s16* pB2 = pB0 + (size_t)128*K;
  const s16* pB3 = pB0 + (size_t)192*K;

  int abase = (wm*64 + lrow) * 64;
  int bbase = (wn*32 + lrow) * 64;
  int sw0 = ((lq ^ s) << 3);           // kk=0  -> c8 = lq
  int sw1 = (((4 + lq) ^ s) << 3);     // kk=32 -> c8 = 4+lq

  const s16* rA0s0 = lds + abase + sw0;
  const s16* rA0s1 = lds + abase + sw1;
  const s16* rA1s0 = lds + 4*8192 + abase + sw0;
  const s16* rA1s1 = lds + 4*8192 + abase + sw1;
  const s16* rB0s0 = lds + 2*8192 + bbase + sw0;
  const s16* rB0s1 = lds + 2*8192 + bbase + sw1;
  const s16* rB1s0 = lds + 6*8192 + bbase + sw0;
  const s16* rB1s1 = lds + 6*8192 + bbase + sw1;

  f32x4 acc[2][4][2][2];
  #pragma unroll
  for (int a = 0; a < 2; ++a)
    #pragma unroll
    for (int b = 0; b < 4; ++b)
      #pragma unroll
      for (int c = 0; c < 2; ++c)
        #pragma unroll
        for (int d = 0; d < 2; ++d) acc[a][b][c][d] = (f32x4){0.f,0.f,0.f,0.f};

  short8 af[2][4];                     // A frag (A0 at P1/P2, A1 at P3/P4)
  short8 bf0[2][2], bf1[2][2];         // B0 / B1 frags

#define STGA0(buf) do{ gl2lds16(pA0, lds+((buf)*4+0)*8192+wo); gl2lds16(pA1, lds+((buf)*4+0)*8192+4096+wo); pA0+=64; pA1+=64; }while(0)
#define STGA1(buf) do{ gl2lds16(pA2, lds+((buf)*4+1)*8192+wo); gl2lds16(pA3, lds+((buf)*4+1)*8192+4096+wo); pA2+=64; pA3+=64; }while(0)
#define STGB0(buf) do{ gl2lds16(pB0, lds+((buf)*4+2)*8192+wo); gl2lds16(pB1, lds+((buf)*4+2)*8192+4096+wo); pB0+=64; pB1+=64; }while(0)
#define STGB1(buf) do{ gl2lds16(pB2, lds+((buf)*4+3)*8192+wo); gl2lds16(pB3, lds+((buf)*4+3)*8192+4096+wo); pB2+=64; pB3+=64; }while(0)
#define RDAF(buf,mh) do{ _Pragma("unroll") for (int m_ = 0; m_ < 4; ++m_){ \
    af[0][m_] = *(const short8*)(rA##buf##s0 + (mh)*8192 + m_*1024); \
    af[1][m_] = *(const short8*)(rA##buf##s1 + (mh)*8192 + m_*1024); } }while(0)
#define RDBF(buf,nh,dst) do{ _Pragma("unroll") for (int n_ = 0; n_ < 2; ++n_){ \
    dst[0][n_] = *(const short8*)(rB##buf##s0 + (nh)*8192 + n_*1024); \
    dst[1][n_] = *(const short8*)(rB##buf##s1 + (nh)*8192 + n_*1024); } }while(0)
#define MFMA_Q(mh,nh,B_) do{ __builtin_amdgcn_s_setprio(1); \
    _Pragma("unroll") for (int kk_ = 0; kk_ < 2; ++kk_) \
      _Pragma("unroll") for (int m_ = 0; m_ < 4; ++m_) \
        _Pragma("unroll") for (int n_ = 0; n_ < 2; ++n_) \
          acc[mh][m_][nh][n_] = __builtin_amdgcn_mfma_f32_16x16x32_bf16( \
              af[kk_][m_], B_[kk_][n_], acc[mh][m_][nh][n_], 0, 0, 0); \
    __builtin_amdgcn_s_setprio(0); }while(0)

#define TILE(c,n) do{ \
    /* P1 */ RDAF(c,0); RDBF(c,0,bf0); STGA1(n); \
    BARR(); LGKM0(); MFMA_Q(0,0,bf0); BARR(); \
    /* P2 */ RDBF(c,1,bf1); STGA0(c); \
    BARR(); LGKM0(); MFMA_Q(0,1,bf1); BARR(); \
    /* P3 */ RDAF(c,1); STGB0(c); \
    BARR(); LGKM0(); MFMA_Q(1,0,bf0); BARR(); \
    /* P4 */ STGB1(c); VMW(6); \
    BARR(); MFMA_Q(1,1,bf1); BARR(); }while(0)

  int NT = K >> 6;                     // NT even: pairs + 2-tile tail
  // prologue: tile0 {A0,B0,B1,A1} + tile1 {A0,B0,B1}; retire tile0.
  STGA0(0); STGB0(0); STGB1(0); STGA1(0);
  STGA0(1); STGB0(1); STGB1(1);
  VMW(6); BARR();

  for (int it = 0; it < (NT-2)/2; ++it){
    TILE(0,1);
    TILE(1,0);
  }
  { // tile NT-2 (c=0): stage only A1(NT-1)->buf1; drain fully at P4
    RDAF(0,0); RDBF(0,0,bf0); STGA1(1);
    BARR(); LGKM0(); MFMA_Q(0,0,bf0); BARR();
    RDBF(0,1,bf1);
    BARR(); LGKM0(); MFMA_Q(0,1,bf1); BARR();
    RDAF(0,1);
    BARR(); LGKM0(); MFMA_Q(1,0,bf0); BARR();
    VMW(0);
    BARR(); MFMA_Q(1,1,bf1); BARR();
    // tile NT-1 (c=1): pure compute
    RDAF(1,0); RDBF(1,0,bf0);
    BARR(); LGKM0(); MFMA_Q(0,0,bf0); BARR();
    RDBF(1,1,bf1);
    BARR(); LGKM0(); MFMA_Q(0,1,bf1); BARR();
    RDAF(1,1);
    LGKM0(); MFMA_Q(1,0,bf0);
    MFMA_Q(1,1,bf1);
  }
#undef TILE
#undef STGA0
#undef STGA1
#undef STGB0
#undef STGB1
#undef RDAF
#undef RDBF
#undef MFMA_Q

  bool do_gelu = flags & 1;
  #pragma unroll
  for (int nh = 0; nh < 2; ++nh){
    #pragma unroll
    for (int nj = 0; nj < 2; ++nj){
      int col = n0 + wn*32 + nh*128 + nj*16 + lrow;
      float bcol = bias ? bias[col] : 0.f;
      #pragma unroll
      for (int mh = 0; mh < 2; ++mh){
        #pragma unroll
        for (int m = 0; m < 4; ++m){
          int row_base = m0 + wm*64 + mh*128 + m*16 + lq*4;
          #pragma unroll
          for (int r = 0; r < 4; ++r){
            float val = acc[mh][m][nh][nj][r] + bcol;
            if (do_gelu) val = 0.5f * val * (1.f + erff(val * 0.70710678118654752f));
            Cb[(size_t)(row_base + r) * N + col] = f2bf(val);
          }
        }
      }
    }
  }
}

// ============ 256x128 bf16 GEMM — same m201 phase template (2 phases) =======
// N=1024 outputs (Wo, W2): 256 blocks (1/CU), 96KB LDS.
// P1: rd{A0->af, B->bf} stg A1(t+1)->n.A1; BARR; lgkm0; MFMA0; BARR.
// P2: rd{A1->af} stg {A0,B}(t+2)->c, VMW(4); BARR; lgkm0; MFMA1; BARR.
// vmcnt: 4 at tile start, +6/tile, VMW(4)@P2 retires tile t+1 (6 loads).
__global__ __launch_bounds__(512,2) void gemm256h(const s16* __restrict__ A,
                                                  const s16* __restrict__ Bt,
                                                  int N, int K,
                                                  float* __restrict__ Cf,
                                                  s16* __restrict__ Cb,
                                                  const float* __restrict__ bias,
                                                  const float* __restrict__ resid,
                                                  int flags, int tiles_y){
  __shared__ s16 lds[2*3*8192];   // [buf][slot: A0,A1,B][128*64]
  int t = threadIdx.x;
  int tx, ty; xcd_tile(tiles_y, tx, ty);
  int m0 = ty * 256, n0 = tx * 128;
  int w = t >> 6, lane = t & 63;
  int wm = w >> 2, wn = w & 3;         // 2M x 4N
  int lrow = lane & 15, lq = lane >> 4;
  int s = lrow & 7;

  int grow = t >> 3;
  int g = (t & 7) ^ (grow & 7);
  int wo = w * 512;

  const s16* pA0 = A  + (size_t)(m0 + grow) * K + g*8;
  const s16* pA1 = pA0 + (size_t)64*K;
  const s16* pA2 = pA0 + (size_t)128*K;
  const s16* pA3 = pA0 + (size_t)192*K;
  const s16* pB0 = Bt + (size_t)(n0 + grow) * K + g*8;
  const s16* pB1 = pB0 + (size_t)64*K;

  int abase = (wm*64 + lrow) * 64;
  int bbase = (wn*32 + lrow) * 64;
  int sw0 = ((lq ^ s) << 3);
  int sw1 = (((4 + lq) ^ s) << 3);

  const s16* rA0s0 = lds + abase + sw0;
  const s16* rA0s1 = lds + abase + sw1;
  const s16* rA1s0 = lds + 3*8192 + abase + sw0;
  const s16* rA1s1 = lds + 3*8192 + abase + sw1;
  const s16* rB0s0 = lds + 2*8192 + bbase + sw0;
  const s16* rB0s1 = lds + 2*8192 + bbase + sw1;
  const s16* rB1s0 = lds + 5*8192 + bbase + sw0;
  const s16* rB1s1 = lds + 5*8192 + bbase + sw1;

  f32x4 acc[2][4][2];                  // [mh][m][nj]
  #pragma unroll
  for (int a = 0; a < 2; ++a)
    #pragma unroll
    for (int b = 0; b < 4; ++b)
      #pragma unroll
      for (int c = 0; c < 2; ++c) acc[a][b][c] = (f32x4){0.f,0.f,0.f,0.f};

  short8 af[2][4];                     // A frag (A0 at P1, A1 at P2)
  short8 bf[2][2];                     // B frag (whole tile)

#define STGHA0(buf) do{ gl2lds16(pA0, lds+((buf)*3+0)*8192+wo); gl2lds16(pA1, lds+((buf)*3+0)*8192+4096+wo); pA0+=64; pA1+=64; }while(0)
#define STGHA1(buf) do{ gl2lds16(pA2, lds+((buf)*3+1)*8192+wo); gl2lds16(pA3, lds+((buf)*3+1)*8192+4096+wo); pA2+=64; pA3+=64; }while(0)
#define STGHB(buf)  do{ gl2lds16(pB0, lds+((buf)*3+2)*8192+wo); gl2lds16(pB1, lds+((buf)*3+2)*8192+4096+wo); pB0+=64; pB1+=64; }while(0)
#define RDAH(buf,mh) do{ _Pragma("unroll") for (int m_ = 0; m_ < 4; ++m_){ \
    af[0][m_] = *(const short8*)(rA##buf##s0 + (mh)*8192 + m_*1024); \
    af[1][m_] = *(const short8*)(rA##buf##s1 + (mh)*8192 + m_*1024); } }while(0)
#define RDBH(buf) do{ _Pragma("unroll") for (int n_ = 0; n_ < 2; ++n_){ \
    bf[0][n_] = *(const short8*)(rB##buf##s0 + n_*1024); \
    bf[1][n_] = *(const short8*)(rB##buf##s1 + n_*1024); } }while(0)
#define MFMA_H(mh) do{ __builtin_amdgcn_s_setprio(1); \
    _Pragma("unroll") for (int kk_ = 0; kk_ < 2; ++kk_) \
      _Pragma("unroll") for (int m_ = 0; m_ < 4; ++m_) \
        _Pragma("unroll") for (int n_ = 0; n_ < 2; ++n_) \
          acc[mh][m_][n_] = __builtin_amdgcn_mfma_f32_16x16x32_bf16( \
              af[kk_][m_], bf[kk_][n_], acc[mh][m_][n_], 0, 0, 0); \
    __builtin_amdgcn_s_setprio(0); }while(0)

#define TILEH(c,n) do{ \
    /* P1 */ RDAH(c,0); RDBH(c); STGHA1(n); \
    BARR(); LGKM0(); MFMA_H(0); BARR(); \
    /* P2 */ RDAH(c,1); STGHA0(c); STGHB(c); VMW(4); \
    BARR(); LGKM0(); MFMA_H(1); BARR(); }while(0)

  int NT = K >> 6;
  // prologue: tile0 {A0,B,A1} + tile1 {A0,B}; retire tile0.
  STGHA0(0); STGHB(0); STGHA1(0);
  STGHA0(1); STGHB(1);
  VMW(4); BARR();

  for (int it = 0; it < (NT-2)/2; ++it){
    TILEH(0,1);
    TILEH(1,0);
  }
  { // tile NT-2 (c=0): stage only A1(NT-1)->buf1; drain at P2
    RDAH(0,0); RDBH(0); STGHA1(1);
    BARR(); LGKM0(); MFMA_H(0); BARR();
    RDAH(0,1);
    VMW(0);
    BARR(); LGKM0(); MFMA_H(1); BARR();
    // tile NT-1 (c=1): pure compute
    RDAH(1,0); RDBH(1);
    BARR(); LGKM0(); MFMA_H(0); BARR();
    RDAH(1,1);
    LGKM0(); MFMA_H(1);
  }
#undef TILEH
#undef STGHA0
#undef STGHA1
#undef STGHB
#undef RDAH
#undef RDBH
#undef MFMA_H

  bool do_gelu = flags & 1;
  bool out_bf = flags & 2;
  #pragma unroll
  for (int nj = 0; nj < 2; ++nj){
    int col = n0 + wn*32 + nj*16 + lrow;
    float bcol = bias ? bias[col] : 0.f;
    #pragma unroll
    for (int mh = 0; mh < 2; ++mh){
      #pragma unroll
      for (int m = 0; m < 4; ++m){
        int row_base = m0 + wm*64 + mh*128 + m*16 + lq*4;
        #pragma unroll
        for (int r = 0; r < 4; ++r){
          int grow_ = row_base + r;
          float val = acc[mh][m][nj][r] + bcol;
          if (do_gelu) val = 0.5f * val * (1.f + erff(val * 0.70710678118654752f));
          if (resid) val += resid[(size_t)grow_ * N + col];
          if (out_bf) Cb[(size_t)grow_ * N + col] = f2bf(val);
          else        Cf[(size_t)grow_ * N + col] = val;
        }
      }
    }
  }
}

// ---------------- retention 2a (per batch): U_t[dv][dk] = (d_k*k (x) v)^T ----
// grid 512 = h(8) + n(64); k,v from fused qkv (row stride 4096)
__global__ __launch_bounds__(256,2) void ret_chunksum(const s16* __restrict__ k,
                                                      const s16* __restrict__ v,
                                                      s16* __restrict__ U){
  int bi = blockIdx.x;
  int h = bi & 7, n = bi >> 3;
  int t = threadIdx.x;
  __shared__ s16 ks[128*72];   // ks[dk][s], d_k decay folded
  __shared__ s16 vs[256*72];   // vs[dv][s]
  float log2b = log2f(1.f - exp2f(-5.f - (float)h));
  const s16* kbase = k + (size_t)(n*64)*4096 + h*128;
  const s16* vbase = v + (size_t)(n*64)*4096 + h*256;
  #pragma unroll
  for (int i = 0; i < 4; ++i){
    int e = i*2048 + t*8;
    int s = e >> 7, dk = e & 127;
    int4 kv = *(const int4*)(kbase + (size_t)s*4096 + dk);
    float f[8]; unpack8(kv, f);
    float dec = exp2f(log2b * (float)(63 - s));
    #pragma unroll
    for (int j = 0; j < 8; ++j) ks[(dk+j)*72 + s] = f2bf(f[j]*dec);
  }
  #pragma unroll
  for (int i = 0; i < 8; ++i){
    int e = i*2048 + t*8;
    int s = e >> 8, dv = e & 255;
    int4 vv = *(const int4*)(vbase + (size_t)s*4096 + dv);
    s16 tmp[8]; *(int4*)tmp = vv;
    #pragma unroll
    for (int j = 0; j < 8; ++j) vs[(dv+j)*72 + s] = tmp[j];
  }
  __syncthreads();
  int w = t >> 6, lane = t & 63;
  int m0w = w*64;   // dv rows, 4 tiles per wave
  int lrow = lane & 15, lq = lane >> 4;
  f32x4 acc[4][8];
  #pragma unroll
  for (int mi = 0; mi < 4; ++mi)
    #pragma unroll
    for (int ni = 0; ni < 8; ++ni) acc[mi][ni] = (f32x4){0.f,0.f,0.f,0.f};
  #pragma unroll
  for (int kk = 0; kk < 64; kk += 32){
    short8 af[4], bfr[8];
    #pragma unroll
    for (int mi = 0; mi < 4; ++mi)
      af[mi] = *(short8*)&vs[(m0w + mi*16 + lrow)*72 + kk + lq*8];
    #pragma unroll
    for (int ni = 0; ni < 8; ++ni)
      bfr[ni] = *(short8*)&ks[(ni*16 + lrow)*72 + kk + lq*8];
    #pragma unroll
    for (int mi = 0; mi < 4; ++mi)
      #pragma unroll
      for (int ni = 0; ni < 8; ++ni)
        acc[mi][ni] = __builtin_amdgcn_mfma_f32_16x16x32_bf16(af[mi], bfr[ni], acc[mi][ni], 0, 0, 0);
  }
  s16* Ub = U + ((size_t)(h*64 + n))*32768;
  #pragma unroll
  for (int mi = 0; mi < 4; ++mi)
    #pragma unroll
    for (int ni = 0; ni < 8; ++ni)
      #pragma unroll
      for (int r = 0; r < 4; ++r){
        int row = m0w + mi*16 + lq*4 + r;   // dv
        int col = ni*16 + lrow;             // dk
        Ub[(size_t)row*128 + col] = f2bf(acc[mi][ni][r]);
      }
}

// ---------------- retention 2b (per batch): in-place decay prefix scan -------
__global__ __launch_bounds__(256) void ret_scan(s16* __restrict__ US){
  int tid = blockIdx.x*256 + threadIdx.x;       // 32768 threads
  int h = tid >> 12;
  int rem = tid & 4095;
  int dv = rem >> 4, dk0 = (rem & 15)*8;
  float log2b = log2f(1.f - exp2f(-5.f - (float)h));
  float dc = exp2f(log2b * 64.f);
  s16* base = US + (size_t)h*64*32768 + (size_t)dv*128 + dk0;
  float acc[8] = {0.f,0.f,0.f,0.f,0.f,0.f,0.f,0.f};
  #pragma unroll 4
  for (int n = 0; n < 64; ++n){
    s16* p = base + (size_t)n*32768;
    int4 u4 = *(const int4*)p;
    float uf[8]; unpack8(u4, uf);
    s16 sb[8];
    #pragma unroll
    for (int j = 0; j < 8; ++j) sb[j] = f2bf(acc[j]);
    *(int4*)p = *(int4*)sb;
    #pragma unroll
    for (int j = 0; j < 8; ++j) acc[j] = acc[j]*dc + uf[j];
  }
}

// ---------------- retention fused (per batch): O = mask(qk^T)@v + dq*(q@S) ---
// grid 512 = h(8) + n(64). q,k,v from fused qkv (stride 4096); S_t [h][n][256][128]
__global__ __launch_bounds__(256,2) void ret_attn(const s16* __restrict__ q,
                                                  const s16* __restrict__ k,
                                                  const s16* __restrict__ v,
                                                  const s16* __restrict__ S,
                                                  s16* __restrict__ o){
  int bi = blockIdx.x;
  int h = bi & 7, n = bi >> 3;
  int t = threadIdx.x;
  int w = t >> 6, lane = t & 63;
  int lrow = lane & 15, lq = lane >> 4;
  float log2b = log2f(1.f - exp2f(-5.f - (float)h));
  __shared__ s16 As[64*72];    // masked scores, A-operand staging
  __shared__ s16 vs[256*72];   // v^T [dv][s]

  // stage v transposed
  const s16* vbase = v + (size_t)(n*64)*4096 + h*256;
  #pragma unroll
  for (int i = 0; i < 8; ++i){
    int e = i*2048 + t*8;
    int s = e >> 8, dv = e & 255;
    int4 vv = *(const int4*)(vbase + (size_t)s*4096 + dv);
    s16 tmp[8]; *(int4*)tmp = vv;
    #pragma unroll
    for (int j = 0; j < 8; ++j) vs[(dv+j)*72 + s] = tmp[j];
  }

  // phase 1: wave w computes A[:, 16w:16w+16] = q @ k^T, masked
  const s16* qbase = q + (size_t)(n*64)*4096 + h*128;
  const s16* kbase = k + (size_t)(n*64)*4096 + h*128;
  short8 qf[4][4];   // [row-tile][kstep], reused in phase 2
  #pragma unroll
  for (int ti = 0; ti < 4; ++ti)
    #pragma unroll
    for (int c = 0; c < 4; ++c)
      qf[ti][c] = *(const short8*)(qbase + (size_t)(ti*16 + lrow)*4096 + c*32 + lq*8);
  short8 kf[4];
  #pragma unroll
  for (int c = 0; c < 4; ++c)
    kf[c] = *(const short8*)(kbase + (size_t)(16*w + lrow)*4096 + c*32 + lq*8);
  #pragma unroll
  for (int ti = 0; ti < 4; ++ti){
    f32x4 acc_a = (f32x4){0.f,0.f,0.f,0.f};
    #pragma unroll
    for (int c = 0; c < 4; ++c)
      acc_a = __builtin_amdgcn_mfma_f32_16x16x32_bf16(qf[ti][c], kf[c], acc_a, 0, 0, 0);
    #pragma unroll
    for (int r = 0; r < 4; ++r){
      int ti_idx = ti*16 + lq*4 + r;
      int s_idx = 16*w + lrow;
      int d = ti_idx - s_idx;
      float val = (d >= 0) ? acc_a[r] * exp2f(log2b * (float)d) : 0.f;
      As[ti_idx*72 + s_idx] = f2bf(val);
    }
  }
  __syncthreads();

  // phase 2: wave w owns dv cols [64w, 64w+64)
  f32x4 acc[4][4];
  #pragma unroll
  for (int mi = 0; mi < 4; ++mi)
    #pragma unroll
    for (int nj = 0; nj < 4; ++nj) acc[mi][nj] = (f32x4){0.f,0.f,0.f,0.f};

  // q @ S  (K = 128)
  const s16* Sbase = S + ((size_t)(h*64 + n)*256 + w*64)*128;
  #pragma unroll
  for (int c = 0; c < 4; ++c){
    short8 bf[4];
    #pragma unroll
    for (int nj = 0; nj < 4; ++nj)
      bf[nj] = *(const short8*)(Sbase + (size_t)(nj*16 + lrow)*128 + c*32 + lq*8);
    #pragma unroll
    for (int mi = 0; mi < 4; ++mi)
      #pragma unroll
      for (int nj = 0; nj < 4; ++nj)
        acc[mi][nj] = __builtin_amdgcn_mfma_f32_16x16x32_bf16(qf[mi][c], bf[nj], acc[mi][nj], 0, 0, 0);
  }
  // scale by d_q = b^(row+1)
  #pragma unroll
  for (int mi = 0; mi < 4; ++mi){
    #pragma unroll
    for (int r = 0; r < 4; ++r){
      float dq = exp2f(log2b * (float)(mi*16 + lq*4 + r + 1));
      #pragma unroll
      for (int nj = 0; nj < 4; ++nj) acc[mi][nj][r] *= dq;
    }
  }
  // A @ v  (K = 64)
  #pragma unroll
  for (int c = 0; c < 2; ++c){
    short8 af[4], bf[4];
    #pragma unroll
    for (int mi = 0; mi < 4; ++mi)
      af[mi] = *(short8*)&As[(mi*16 + lrow)*72 + c*32 + lq*8];
    #pragma unroll
    for (int nj = 0; nj < 4; ++nj)
      bf[nj] = *(short8*)&vs[(w*64 + nj*16 + lrow)*72 + c*32 + lq*8];
    #pragma unroll
    for (int mi = 0; mi < 4; ++mi)
      #pragma unroll
      for (int nj = 0; nj < 4; ++nj)
        acc[mi][nj] = __builtin_amdgcn_mfma_f32_16x16x32_bf16(af[mi], bf[nj], acc[mi][nj], 0, 0, 0);
  }
  // write O
  s16* obase = o + (size_t)(n*64)*2048 + h*256;
  #pragma unroll
  for (int mi = 0; mi < 4; ++mi)
    #pragma unroll
    for (int nj = 0; nj < 4; ++nj)
      #pragma unroll
      for (int r = 0; r < 4; ++r){
        int row = mi*16 + lq*4 + r;
        int col = w*64 + nj*16 + lrow;
        obase[(size_t)row*2048 + col] = f2bf(acc[mi][nj][r]);
      }
}

extern "C" void kernel_launch(void* const* d_in, const int* in_sizes, int n_in,
                              void* d_out, int out_size, void* d_ws, size_t ws_size,
                              hipStream_t stream) {
  (void)in_sizes; (void)n_in; (void)out_size; (void)ws_size;
  const float* x     = (const float*)d_in[0];
  const float* ln1_w = (const float*)d_in[1];
  const float* ln1_b = (const float*)d_in[2];
  const float* Wq    = (const float*)d_in[3];
  const float* Wk    = (const float*)d_in[4];
  const float* Wv    = (const float*)d_in[5];
  const float* Wo    = (const float*)d_in[6];
  const float* ln2_w = (const float*)d_in[7];
  const float* ln2_b = (const float*)d_in[8];
  const float* W1    = (const float*)d_in[9];
  const float* b1    = (const float*)d_in[10];
  const float* W2    = (const float*)d_in[11];
  const float* b2    = (const float*)d_in[12];
  float* out = (float*)d_out;
  char* ws = (char*)d_ws;

  // ---- static arena, peak 172 MB (lifetime-aliased) ----
  const size_t MB = 1ull << 20;
  s16* Wqkv_t = (s16*)(ws + 0*MB);   // [0,8)  rows: 0-1023 q, 1024-2047 k, 2048-4095 v
  s16* Wo_t = (s16*)(ws + 8*MB);     // [8,12)
  s16* W1_t = (s16*)(ws + 12*MB);    // [12,20)
  s16* W2_t = (s16*)(ws + 20*MB);    // [20,28)
  s16* hbuf = (s16*)(ws + 28*MB);    // [28,44)  dead after QKV gemm
  s16* h2   = (s16*)(ws + 28*MB);    // [28,44)  alias dead hbuf (post-retention)
  s16* qkv  = (s16*)(ws + 44*MB);    // [44,108) [8192,4096] bf16, dead after ret_attn(b1)
  float* x1 = (float*)(ws + 44*MB);  // [44,76)  alias dead qkv head (post-retention)
  s16* fb   = (s16*)(ws + 76*MB);    // [76,140) alias dead qkv tail + US (FFN acts)
  s16* US   = (s16*)(ws + 108*MB);   // [108,140) bf16 per-batch U->S (in-place scan)
  s16* ob   = (s16*)(ws + 140*MB);   // [140,172)

  // weight transpose-convert (DK^-0.5 folded into Wq)
  conv_t<<<dim3(32,32),  256, 0, stream>>>(Wq, Wqkv_t, 1024, 1024, 0.08838834764831845f);
  conv_t<<<dim3(32,32),  256, 0, stream>>>(Wk, Wqkv_t + (size_t)1024*1024, 1024, 1024, 1.f);
  conv_t<<<dim3(64,32),  256, 0, stream>>>(Wv, Wqkv_t + (size_t)2048*1024, 1024, 2048, 1.f);
  conv_t<<<dim3(32,64),  256, 0, stream>>>(Wo, Wo_t, 2048, 1024, 1.f);
  conv_t<<<dim3(128,32), 256, 0, stream>>>(W1, W1_t, 1024, 4096, 1.f);
  conv_t<<<dim3(32,128), 256, 0, stream>>>(W2, W2_t, 4096, 1024, 1.f);

  ln_bf16<<<8192, 256, 0, stream>>>(x, ln1_w, ln1_b, hbuf);

  // fused QKV: [8192,4096] = hbuf @ Wqkv^T  (256^2 pipelined, 512 blocks)
  gemm256<<<512, 512, 0, stream>>>(hbuf, Wqkv_t, 4096, 1024, qkv, nullptr, 0, 32);

  for (int b = 0; b < 2; ++b){
    const s16* q_b = qkv + (size_t)b*4096*4096;
    const s16* k_b = q_b + 1024;
    const s16* v_b = q_b + 2048;
    s16* ob_b = ob + (size_t)b*4096*2048;
    ret_chunksum<<<512, 256, 0, stream>>>(k_b, v_b, US);
    ret_scan<<<128, 256, 0, stream>>>(US);
    ret_attn<<<512, 256, 0, stream>>>(q_b, k_b, v_b, US, ob_b);
  }

  // Wo: x1 = x + ob @ Wo^T   (256x128 pipelined, 256 blocks, tiles_y=32)
  gemm256h<<<256, 512, 0, stream>>>(ob, Wo_t, 1024, 2048, x1, nullptr, nullptr, x, 0, 32);
  ln_bf16<<<8192, 256, 0, stream>>>(x1, ln2_w, ln2_b, h2);

  // FFN: fb = gelu(h2 @ W1^T + b1)  [8192,4096]  (256^2 pipelined)
  gemm256<<<512, 512, 0, stream>>>(h2, W1_t, 4096, 1024, fb, b1, 1, 32);
  // out = x1 + b2 + fb @ W2^T   (256x128 pipelined, 256 blocks, K=4096)
  gemm256h<<<256, 512, 0, stream>>>(fb, W2_t, 1024, 4096, out, nullptr, b2, x1, 0, 32);
}

// Round 9
// 583.296 us; speedup vs baseline: 1.0771x; 1.0771x over previous
//
#include <hip/hip_runtime.h>
#include <math.h>

typedef short s16;
typedef __attribute__((ext_vector_type(8))) short short8;
typedef __attribute__((ext_vector_type(4))) float f32x4;

__device__ __forceinline__ float bf2f_lo(unsigned u){ return __builtin_bit_cast(float, u << 16); }
__device__ __forceinline__ float bf2f_hi(unsigned u){ return __builtin_bit_cast(float, u & 0xffff0000u); }
__device__ __forceinline__ float bf2f(unsigned short h){ return __builtin_bit_cast(float, (unsigned)h << 16); }
__device__ __forceinline__ s16 f2bf(float f){
  unsigned u = __builtin_bit_cast(unsigned, f);
  u += 0x7fffu + ((u >> 16) & 1u);
  return (s16)(u >> 16);
}
__device__ __forceinline__ void unpack8(int4 v, float* f){
  unsigned a=(unsigned)v.x, b=(unsigned)v.y, c=(unsigned)v.z, d=(unsigned)v.w;
  f[0]=bf2f_lo(a); f[1]=bf2f_hi(a); f[2]=bf2f_lo(b); f[3]=bf2f_hi(b);
  f[4]=bf2f_lo(c); f[5]=bf2f_hi(c); f[6]=bf2f_lo(d); f[7]=bf2f_hi(d);
}
// async global->LDS 16B: lds dest is wave-uniform base + lane*16.
// r5 lesson: NEVER use the builtin's imm offset (corrupts on gfx950) —
// pass 0 and fold all K-advance into the pointer.
__device__ __forceinline__ void gl2lds16(const s16* g, s16* l){
  __builtin_amdgcn_global_load_lds((const __attribute__((address_space(1))) void*)g,
                                   (__attribute__((address_space(3))) void*)l, 16, 0, 0);
}

// ---------------- LayerNorm (fp32 in) -> bf16 out, D=1024, 1 block/row ------
__global__ __launch_bounds__(256) void ln_bf16(const float* __restrict__ x,
                                               const float* __restrict__ w,
                                               const float* __restrict__ b,
                                               s16* __restrict__ out){
  int row = blockIdx.x; int t = threadIdx.x;
  const float* xr = x + (size_t)row * 1024;
  float4 v = *(const float4*)(xr + t*4);
  float s = v.x + v.y + v.z + v.w;
  float ss = v.x*v.x + v.y*v.y + v.z*v.z + v.w*v.w;
  for (int o = 32; o > 0; o >>= 1){ s += __shfl_down(s, o, 64); ss += __shfl_down(ss, o, 64); }
  __shared__ float red[8];
  int wid = t >> 6, lane = t & 63;
  if (lane == 0){ red[wid] = s; red[4+wid] = ss; }
  __syncthreads();
  if (t == 0){
    float S = red[0]+red[1]+red[2]+red[3];
    float SS = red[4]+red[5]+red[6]+red[7];
    red[0] = S * (1.f/1024.f);
    red[1] = SS * (1.f/1024.f);
  }
  __syncthreads();
  float mu = red[0];
  float var = red[1] - mu*mu;
  float rstd = rsqrtf(var + 1e-6f);
  float vv[4] = {v.x, v.y, v.z, v.w};
  short4 o4;
  s16 tmp[4];
  #pragma unroll
  for (int i = 0; i < 4; ++i){
    int c = t*4 + i;
    float val = (vv[i] - mu) * rstd * w[c] + b[c];
    tmp[i] = f2bf(val);
  }
  o4.x = tmp[0]; o4.y = tmp[1]; o4.z = tmp[2]; o4.w = tmp[3];
  *(short4*)(out + (size_t)row*1024 + t*4) = o4;
}

// ---------------- transpose-convert fp32 W[K,N] -> bf16 Wt[N,K], with scale --
__global__ __launch_bounds__(256) void conv_t(const float* __restrict__ W,
                                              s16* __restrict__ Wt,
                                              int K, int N, float scale){
  __shared__ float tile[32][33];
  int n0 = blockIdx.x * 32, k0 = blockIdx.y * 32;
  int tx = threadIdx.x & 31, ty = threadIdx.x >> 5;   // ty 0..7
  #pragma unroll
  for (int i = 0; i < 4; ++i){
    int r = ty + i*8;
    tile[r][tx] = W[(size_t)(k0 + r)*N + n0 + tx];
  }
  __syncthreads();
  #pragma unroll
  for (int i = 0; i < 4; ++i){
    int r = ty + i*8;
    Wt[(size_t)(n0 + r)*K + k0 + tx] = f2bf(tile[tx][r] * scale);
  }
}

// XCD swizzle: 1D grid, tiles_y M-tiles (divisible by 8). Each XCD owns a
// disjoint M-row stripe (A fetched once, per-XCD L2); N iterated slowly so
// the B-slab stays hot across sy consecutive on-XCD blocks.
__device__ __forceinline__ void xcd_tile(int tiles_y, int& tx, int& ty){
  int id = blockIdx.x;
  int sy = tiles_y >> 3;
  int xcd = id & 7, p = id >> 3;
  ty = xcd * sy + (p % sy);
  tx = p / sy;
}

#define VMW(n) asm volatile("s_waitcnt vmcnt(" #n ")" ::: "memory")
#define BARR() asm volatile("s_barrier" ::: "memory")

// ============ 256x256 bf16 GEMM, shifted reg-pipeline (r4: best, 98.2us) ====
// 4 phases/tile {STG; [VMW]; BARR; RD(frags for NEXT phase); MFMA(this)}.
// Single VMW(6)@P4 retires exactly tile t+1 (6 outstanding at tile start).
// GEMM plateau note (r3-r8): all schedule variants land 650-680 TF
// (MfmaUtil 25-29%) — this r4 form is the empirical best; do not re-derive.
__global__ __launch_bounds__(512,2) void gemm256(const s16* __restrict__ A,
                                                 const s16* __restrict__ Bt,
                                                 int N, int K,
                                                 s16* __restrict__ Cb,
                                                 const float* __restrict__ bias,
                                                 int flags, int tiles_y){
  __shared__ s16 lds[2*4*8192];   // [buf][slot: A0,A1,B0,B1][128*64]
  int t = threadIdx.x;
  int tx, ty; xcd_tile(tiles_y, tx, ty);
  int m0 = ty * 256, n0 = tx * 256;
  int w = t >> 6, lane = t & 63;
  int wm = w >> 2, wn = w & 3;         // 2M x 4N
  int lrow = lane & 15, lq = lane >> 4;
  int s = lrow & 7;

  int grow = t >> 3;                   // 0..63
  int g = (t & 7) ^ (grow & 7);
  const s16* Ag = A  + (size_t)(m0 + grow) * K + g*8;
  const s16* Bg = Bt + (size_t)(n0 + grow) * K + g*8;
  int wo = w * 512;                    // wave dest offset (elems) in 8KB round

  int abase = (wm*64 + lrow) * 64;
  int bbase = (wn*32 + lrow) * 64;
  int sw0 = ((lq ^ s) << 3);           // kk=0  -> c8 = lq
  int sw1 = (((4 + lq) ^ s) << 3);     // kk=32 -> c8 = 4+lq

  f32x4 acc[2][4][2][2];
  #pragma unroll
  for (int a = 0; a < 2; ++a)
    #pragma unroll
    for (int b = 0; b < 4; ++b)
      #pragma unroll
      for (int c = 0; c < 2; ++c)
        #pragma unroll
        for (int d = 0; d < 2; ++d) acc[a][b][c][d] = (f32x4){0.f,0.f,0.f,0.f};

  short8 afA[2][4], afB[2][4];         // A0-half frags / A1-half frags
  short8 bf0[2][2], bf1[2][2];         // B0 / B1 frags

#define STG_A(buf,h,kt) do{ \
    gl2lds16(Ag + (size_t)((h)*128    )*K + (kt)*64, lds + ((buf)*4+(h))*8192 + wo); \
    gl2lds16(Ag + (size_t)((h)*128+ 64)*K + (kt)*64, lds + ((buf)*4+(h))*8192 + 4096 + wo); }while(0)
#define STG_B(buf,nh,kt) do{ \
    gl2lds16(Bg + (size_t)((nh)*128    )*K + (kt)*64, lds + ((buf)*4+2+(nh))*8192 + wo); \
    gl2lds16(Bg + (size_t)((nh)*128+ 64)*K + (kt)*64, lds + ((buf)*4+2+(nh))*8192 + 4096 + wo); }while(0)
#define RD_AF(buf,mh,dst) do{ const s16* p_ = lds + ((buf)*4+(mh))*8192 + abase; \
    _Pragma("unroll") for (int m_ = 0; m_ < 4; ++m_){ \
      dst[0][m_] = *(const short8*)(p_ + m_*1024 + sw0); \
      dst[1][m_] = *(const short8*)(p_ + m_*1024 + sw1); } }while(0)
#define RD_BF(buf,nh,dst) do{ const s16* p_ = lds + ((buf)*4+2+(nh))*8192 + bbase; \
    _Pragma("unroll") for (int n_ = 0; n_ < 2; ++n_){ \
      dst[0][n_] = *(const short8*)(p_ + n_*1024 + sw0); \
      dst[1][n_] = *(const short8*)(p_ + n_*1024 + sw1); } }while(0)
#define MFMA_Q(mh,nh,A_,B_) do{ __builtin_amdgcn_s_setprio(1); \
    _Pragma("unroll") for (int kk_ = 0; kk_ < 2; ++kk_) \
      _Pragma("unroll") for (int m_ = 0; m_ < 4; ++m_) \
        _Pragma("unroll") for (int n_ = 0; n_ < 2; ++n_) \
          acc[mh][m_][nh][n_] = __builtin_amdgcn_mfma_f32_16x16x32_bf16( \
              A_[kk_][m_], B_[kk_][n_], acc[mh][m_][nh][n_], 0, 0, 0); \
    __builtin_amdgcn_s_setprio(0); }while(0)

  int NT = K >> 6;
  // prologue: tile0 fully + {A0,B0,B1}(1); retire tile0; preload P1 frags
  STG_A(0,0,0); STG_B(0,0,0); STG_B(0,1,0); STG_A(0,1,0);
  STG_A(1,0,1); STG_B(1,0,1); STG_B(1,1,1);
  VMW(6); BARR();
  RD_AF(0,0,afA); RD_BF(0,0,bf0);

  for (int kt = 0; kt < NT-2; ++kt){
    int cb = kt & 1, nb = cb ^ 1;
    // P1
    STG_A(nb,1,kt+1);
    BARR();
    RD_BF(cb,1,bf1);
    MFMA_Q(0,0,afA,bf0);
    // P2
    STG_A(cb,0,kt+2);
    BARR();
    RD_AF(cb,1,afB);
    MFMA_Q(0,1,afA,bf1);
    // P3
    STG_B(cb,0,kt+2);
    BARR();
    MFMA_Q(1,0,afB,bf0);
    // P4
    STG_B(cb,1,kt+2);
    VMW(6);
    BARR();
    RD_AF(nb,0,afA); RD_BF(nb,0,bf0);
    MFMA_Q(1,1,afB,bf1);
  }
  { // tile NT-2: stage only A1(NT-1); full drain at P4
    int cb = (NT-2) & 1, nb = cb ^ 1;
    STG_A(nb,1,NT-1);
    BARR(); RD_BF(cb,1,bf1); MFMA_Q(0,0,afA,bf0);
    BARR(); RD_AF(cb,1,afB); MFMA_Q(0,1,afA,bf1);
    BARR(); MFMA_Q(1,0,afB,bf0);
    VMW(0);
    BARR();
    RD_AF(nb,0,afA); RD_BF(nb,0,bf0);
    MFMA_Q(1,1,afB,bf1);
  }
  { // tile NT-1: pure compute
    int cb = (NT-1) & 1;
    BARR(); RD_BF(cb,1,bf1); MFMA_Q(0,0,afA,bf0);
    BARR(); RD_AF(cb,1,afB); MFMA_Q(0,1,afA,bf1);
    BARR(); MFMA_Q(1,0,afB,bf0);
    MFMA_Q(1,1,afB,bf1);
  }
#undef STG_A
#undef STG_B
#undef RD_AF
#undef RD_BF
#undef MFMA_Q

  bool do_gelu = flags & 1;
  #pragma unroll
  for (int nh = 0; nh < 2; ++nh){
    #pragma unroll
    for (int nj = 0; nj < 2; ++nj){
      int col = n0 + wn*32 + nh*128 + nj*16 + lrow;
      float bcol = bias ? bias[col] : 0.f;
      #pragma unroll
      for (int mh = 0; mh < 2; ++mh){
        #pragma unroll
        for (int m = 0; m < 4; ++m){
          int row_base = m0 + wm*64 + mh*128 + m*16 + lq*4;
          #pragma unroll
          for (int r = 0; r < 4; ++r){
            float val = acc[mh][m][nh][nj][r] + bcol;
            if (do_gelu) val = 0.5f * val * (1.f + erff(val * 0.70710678118654752f));
            Cb[(size_t)(row_base + r) * N + col] = f2bf(val);
          }
        }
      }
    }
  }
}

// ============ 256x128 bf16 GEMM, shifted reg-pipeline (r4 form) =============
// N=1024 outputs (Wo, W2): 256 blocks (1/CU), 96KB LDS, 2 phases/tile.
// bf parity via 2-tile unroll. VMW(4)@P2 retires tile t+1 (6 loads).
__global__ __launch_bounds__(512,2) void gemm256h(const s16* __restrict__ A,
                                                  const s16* __restrict__ Bt,
                                                  int N, int K,
                                                  float* __restrict__ Cf,
                                                  s16* __restrict__ Cb,
                                                  const float* __restrict__ bias,
                                                  const float* __restrict__ resid,
                                                  int flags, int tiles_y){
  __shared__ s16 lds[2*3*8192];   // [buf][slot: A0,A1,B][128*64]
  int t = threadIdx.x;
  int tx, ty; xcd_tile(tiles_y, tx, ty);
  int m0 = ty * 256, n0 = tx * 128;
  int w = t >> 6, lane = t & 63;
  int wm = w >> 2, wn = w & 3;         // 2M x 4N
  int lrow = lane & 15, lq = lane >> 4;
  int s = lrow & 7;

  int grow = t >> 3;
  int g = (t & 7) ^ (grow & 7);
  const s16* Ag = A  + (size_t)(m0 + grow) * K + g*8;
  const s16* Bg = Bt + (size_t)(n0 + grow) * K + g*8;
  int wo = w * 512;

  int abase = (wm*64 + lrow) * 64;
  int bbase = (wn*32 + lrow) * 64;
  int sw0 = ((lq ^ s) << 3);
  int sw1 = (((4 + lq) ^ s) << 3);

  f32x4 acc[2][4][2];                  // [mh][m][nj]
  #pragma unroll
  for (int a = 0; a < 2; ++a)
    #pragma unroll
    for (int b = 0; b < 4; ++b)
      #pragma unroll
      for (int c = 0; c < 2; ++c) acc[a][b][c] = (f32x4){0.f,0.f,0.f,0.f};

  short8 afA[2][4], afB[2][4];         // A0 / A1 frags
  short8 bfE[2][2], bfO[2][2];         // B frags, even/odd tile parity

#define STG_A(buf,h,kt) do{ \
    gl2lds16(Ag + (size_t)((h)*128    )*K + (kt)*64, lds + ((buf)*3+(h))*8192 + wo); \
    gl2lds16(Ag + (size_t)((h)*128+ 64)*K + (kt)*64, lds + ((buf)*3+(h))*8192 + 4096 + wo); }while(0)
#define STG_B(buf,kt) do{ \
    gl2lds16(Bg + (size_t)0*K  + (kt)*64, lds + ((buf)*3+2)*8192 + wo); \
    gl2lds16(Bg + (size_t)64*K + (kt)*64, lds + ((buf)*3+2)*8192 + 4096 + wo); }while(0)
#define RD_AH(buf,mh,dst) do{ const s16* p_ = lds + ((buf)*3+(mh))*8192 + abase; \
    _Pragma("unroll") for (int m_ = 0; m_ < 4; ++m_){ \
      dst[0][m_] = *(const short8*)(p_ + m_*1024 + sw0); \
      dst[1][m_] = *(const short8*)(p_ + m_*1024 + sw1); } }while(0)
#define RD_BH(buf,dst) do{ const s16* p_ = lds + ((buf)*3+2)*8192 + bbase; \
    _Pragma("unroll") for (int n_ = 0; n_ < 2; ++n_){ \
      dst[0][n_] = *(const short8*)(p_ + n_*1024 + sw0); \
      dst[1][n_] = *(const short8*)(p_ + n_*1024 + sw1); } }while(0)
#define MFMA_H(mh,A_,B_) do{ __builtin_amdgcn_s_setprio(1); \
    _Pragma("unroll") for (int kk_ = 0; kk_ < 2; ++kk_) \
      _Pragma("unroll") for (int m_ = 0; m_ < 4; ++m_) \
        _Pragma("unroll") for (int n_ = 0; n_ < 2; ++n_) \
          acc[mh][m_][n_] = __builtin_amdgcn_mfma_f32_16x16x32_bf16( \
              A_[kk_][m_], B_[kk_][n_], acc[mh][m_][n_], 0, 0, 0); \
    __builtin_amdgcn_s_setprio(0); }while(0)

  int NT = K >> 6;
  // prologue: tile0 (A0,B,A1) + tile1 (A0,B); retire tile0; preload frags
  STG_A(0,0,0); STG_B(0,0); STG_A(0,1,0);
  STG_A(1,0,1); STG_B(1,1);
  VMW(4); BARR();
  RD_AH(0,0,afA); RD_BH(0,bfE);

  for (int it = 0; it < (NT-2)/2; ++it){
    int kt = 2*it;
    // tile kt (cb=0, CUR=bfE, NXT=bfO)
    STG_A(1,1,kt+1);
    BARR(); RD_AH(0,1,afB); MFMA_H(0,afA,bfE);
    STG_A(0,0,kt+2); STG_B(0,kt+2);
    VMW(4);
    BARR(); RD_AH(1,0,afA); RD_BH(1,bfO); MFMA_H(1,afB,bfE);
    // tile kt+1 (cb=1, CUR=bfO, NXT=bfE)
    STG_A(0,1,kt+2);
    BARR(); RD_AH(1,1,afB); MFMA_H(0,afA,bfO);
    STG_A(1,0,kt+3); STG_B(1,kt+3);
    VMW(4);
    BARR(); RD_AH(0,0,afA); RD_BH(0,bfE); MFMA_H(1,afB,bfO);
  }
  { // tile NT-2 (cb=0): stage only A1(NT-1); drain at P2
    STG_A(1,1,NT-1);
    BARR(); RD_AH(0,1,afB); MFMA_H(0,afA,bfE);
    VMW(0);
    BARR(); RD_AH(1,0,afA); RD_BH(1,bfO); MFMA_H(1,afB,bfE);
    // tile NT-1 (cb=1): pure compute
    BARR(); RD_AH(1,1,afB); MFMA_H(0,afA,bfO);
    MFMA_H(1,afB,bfO);
  }
#undef STG_A
#undef STG_B
#undef RD_AH
#undef RD_BH
#undef MFMA_H

  bool do_gelu = flags & 1;
  bool out_bf = flags & 2;
  #pragma unroll
  for (int nj = 0; nj < 2; ++nj){
    int col = n0 + wn*32 + nj*16 + lrow;
    float bcol = bias ? bias[col] : 0.f;
    #pragma unroll
    for (int mh = 0; mh < 2; ++mh){
      #pragma unroll
      for (int m = 0; m < 4; ++m){
        int row_base = m0 + wm*64 + mh*128 + m*16 + lq*4;
        #pragma unroll
        for (int r = 0; r < 4; ++r){
          int grow_ = row_base + r;
          float val = acc[mh][m][nj][r] + bcol;
          if (do_gelu) val = 0.5f * val * (1.f + erff(val * 0.70710678118654752f));
          if (resid) val += resid[(size_t)grow_ * N + col];
          if (out_bf) Cb[(size_t)grow_ * N + col] = f2bf(val);
          else        Cf[(size_t)grow_ * N + col] = val;
        }
      }
    }
  }
}

// ---------------- retention 2a (per batch): U_t[dv][dk] = (d_k*k (x) v)^T ----
// grid 512 = h(8) + n(64); k,v from fused qkv (row stride 4096).
// Staging v2 (r9): lane-per-dk column loads (2B coalesced) + one aligned
// ds_write_b128 per (dk, s-octet). Old scalar transposed writes put all 64
// lanes on one bank (dk stride 8*144B = 0 mod 32 banks -> ~64-way); b128
// writes ride the odd x36 bank rotation -> <=8-way. Reads unchanged (2-way).
__global__ __launch_bounds__(256,2) void ret_chunksum(const s16* __restrict__ k,
                                                      const s16* __restrict__ v,
                                                      s16* __restrict__ U){
  int bi = blockIdx.x;
  int h = bi & 7, n = bi >> 3;
  int t = threadIdx.x;
  __shared__ s16 ks[128*72];   // ks[dk][s], d_k decay folded
  __shared__ s16 vs[256*72];   // vs[dv][s]
  float log2b = log2f(1.f - exp2f(-5.f - (float)h));
  const s16* kbase = k + (size_t)(n*64)*4096 + h*128;
  const s16* vbase = v + (size_t)(n*64)*4096 + h*256;
  #pragma unroll
  for (int i = 0; i < 4; ++i){          // k: 128 dk x 8 s-octets = 1024 segs
    int seg = i*256 + t;
    int dk = seg & 127, s0 = (seg >> 7) << 3;
    s16 tmp[8];
    #pragma unroll
    for (int j = 0; j < 8; ++j){
      int sI = s0 + j;
      float f = bf2f((unsigned short)kbase[(size_t)sI*4096 + dk]);
      tmp[j] = f2bf(f * exp2f(log2b * (float)(63 - sI)));
    }
    *(int4*)&ks[dk*72 + s0] = *(int4*)tmp;
  }
  #pragma unroll
  for (int i = 0; i < 8; ++i){          // v: 256 dv x 8 s-octets = 2048 segs
    int seg = i*256 + t;
    int dv = seg & 255, s0 = (seg >> 8) << 3;
    s16 tmp[8];
    #pragma unroll
    for (int j = 0; j < 8; ++j) tmp[j] = vbase[(size_t)(s0+j)*4096 + dv];
    *(int4*)&vs[dv*72 + s0] = *(int4*)tmp;
  }
  __syncthreads();
  int w = t >> 6, lane = t & 63;
  int m0w = w*64;   // dv rows, 4 tiles per wave
  int lrow = lane & 15, lq = lane >> 4;
  f32x4 acc[4][8];
  #pragma unroll
  for (int mi = 0; mi < 4; ++mi)
    #pragma unroll
    for (int ni = 0; ni < 8; ++ni) acc[mi][ni] = (f32x4){0.f,0.f,0.f,0.f};
  #pragma unroll
  for (int kk = 0; kk < 64; kk += 32){
    short8 af[4], bfr[8];
    #pragma unroll
    for (int mi = 0; mi < 4; ++mi)
      af[mi] = *(short8*)&vs[(m0w + mi*16 + lrow)*72 + kk + lq*8];
    #pragma unroll
    for (int ni = 0; ni < 8; ++ni)
      bfr[ni] = *(short8*)&ks[(ni*16 + lrow)*72 + kk + lq*8];
    #pragma unroll
    for (int mi = 0; mi < 4; ++mi)
      #pragma unroll
      for (int ni = 0; ni < 8; ++ni)
        acc[mi][ni] = __builtin_amdgcn_mfma_f32_16x16x32_bf16(af[mi], bfr[ni], acc[mi][ni], 0, 0, 0);
  }
  s16* Ub = U + ((size_t)(h*64 + n))*32768;
  #pragma unroll
  for (int mi = 0; mi < 4; ++mi)
    #pragma unroll
    for (int ni = 0; ni < 8; ++ni)
      #pragma unroll
      for (int r = 0; r < 4; ++r){
        int row = m0w + mi*16 + lq*4 + r;   // dv
        int col = ni*16 + lrow;             // dk
        Ub[(size_t)row*128 + col] = f2bf(acc[mi][ni][r]);
      }
}

// ---------------- retention 2b (per batch): in-place decay prefix scan -------
// v2 (r9): 4-elem threads (65536 = 256 blocks -> 1 wave/SIMD, 2x the old
// 0.5) + depth-2 explicit prefetch to hide the ~900cy dependent HBM walk.
__global__ __launch_bounds__(256) void ret_scan(s16* __restrict__ US){
  int tid = blockIdx.x*256 + threadIdx.x;       // 65536 threads
  int h = tid >> 13;
  int rem = tid & 8191;
  int dv = rem >> 5, dk0 = (rem & 31)*4;
  float log2b = log2f(1.f - exp2f(-5.f - (float)h));
  float dc = exp2f(log2b * 64.f);
  s16* base = US + (size_t)h*64*32768 + (size_t)dv*128 + dk0;
  float acc[4] = {0.f,0.f,0.f,0.f};
  int2 u0 = *(const int2*)(base);
  int2 u1 = *(const int2*)(base + 32768);
  #pragma unroll 2
  for (int nn = 0; nn < 62; ++nn){
    int2 cur = u0; u0 = u1;
    u1 = *(const int2*)(base + (size_t)(nn+2)*32768);
    s16 sb[4];
    #pragma unroll
    for (int j = 0; j < 4; ++j) sb[j] = f2bf(acc[j]);
    *(int2*)(base + (size_t)nn*32768) = *(int2*)sb;
    unsigned a=(unsigned)cur.x, b=(unsigned)cur.y;
    float uf[4] = {bf2f_lo(a), bf2f_hi(a), bf2f_lo(b), bf2f_hi(b)};
    #pragma unroll
    for (int j = 0; j < 4; ++j) acc[j] = acc[j]*dc + uf[j];
  }
  #pragma unroll
  for (int nn = 62; nn < 64; ++nn){
    int2 cur = u0; u0 = u1;
    s16 sb[4];
    #pragma unroll
    for (int j = 0; j < 4; ++j) sb[j] = f2bf(acc[j]);
    *(int2*)(base + (size_t)nn*32768) = *(int2*)sb;
    unsigned a=(unsigned)cur.x, b=(unsigned)cur.y;
    float uf[4] = {bf2f_lo(a), bf2f_hi(a), bf2f_lo(b), bf2f_hi(b)};
    #pragma unroll
    for (int j = 0; j < 4; ++j) acc[j] = acc[j]*dc + uf[j];
  }
}

// ---------------- retention fused (per batch): O = mask(qk^T)@v + dq*(q@S) ---
// grid 512 = h(8) + n(64). q,k,v from fused qkv (stride 4096); S_t [h][n][256][128]
// v-staging: same column-load b128 scheme as ret_chunksum (r9).
__global__ __launch_bounds__(256,2) void ret_attn(const s16* __restrict__ q,
                                                  const s16* __restrict__ k,
                                                  const s16* __restrict__ v,
                                                  const s16* __restrict__ S,
                                                  s16* __restrict__ o){
  int bi = blockIdx.x;
  int h = bi & 7, n = bi >> 3;
  int t = threadIdx.x;
  int w = t >> 6, lane = t & 63;
  int lrow = lane & 15, lq = lane >> 4;
  float log2b = log2f(1.f - exp2f(-5.f - (float)h));
  __shared__ s16 As[64*72];    // masked scores, A-operand staging
  __shared__ s16 vs[256*72];   // v^T [dv][s]

  // stage v transposed: lane-per-dv column loads, b128 writes
  const s16* vbase = v + (size_t)(n*64)*4096 + h*256;
  #pragma unroll
  for (int i = 0; i < 8; ++i){
    int seg = i*256 + t;
    int dv = seg & 255, s0 = (seg >> 8) << 3;
    s16 tmp[8];
    #pragma unroll
    for (int j = 0; j < 8; ++j) tmp[j] = vbase[(size_t)(s0+j)*4096 + dv];
    *(int4*)&vs[dv*72 + s0] = *(int4*)tmp;
  }

  // phase 1: wave w computes A[:, 16w:16w+16] = q @ k^T, masked
  const s16* qbase = q + (size_t)(n*64)*4096 + h*128;
  const s16* kbase = k + (size_t)(n*64)*4096 + h*128;
  short8 qf[4][4];   // [row-tile][kstep], reused in phase 2
  #pragma unroll
  for (int ti = 0; ti < 4; ++ti)
    #pragma unroll
    for (int c = 0; c < 4; ++c)
      qf[ti][c] = *(const short8*)(qbase + (size_t)(ti*16 + lrow)*4096 + c*32 + lq*8);
  short8 kf[4];
  #pragma unroll
  for (int c = 0; c < 4; ++c)
    kf[c] = *(const short8*)(kbase + (size_t)(16*w + lrow)*4096 + c*32 + lq*8);
  #pragma unroll
  for (int ti = 0; ti < 4; ++ti){
    f32x4 acc_a = (f32x4){0.f,0.f,0.f,0.f};
    #pragma unroll
    for (int c = 0; c < 4; ++c)
      acc_a = __builtin_amdgcn_mfma_f32_16x16x32_bf16(qf[ti][c], kf[c], acc_a, 0, 0, 0);
    #pragma unroll
    for (int r = 0; r < 4; ++r){
      int ti_idx = ti*16 + lq*4 + r;
      int s_idx = 16*w + lrow;
      int d = ti_idx - s_idx;
      float val = (d >= 0) ? acc_a[r] * exp2f(log2b * (float)d) : 0.f;
      As[ti_idx*72 + s_idx] = f2bf(val);
    }
  }
  __syncthreads();

  // phase 2: wave w owns dv cols [64w, 64w+64)
  f32x4 acc[4][4];
  #pragma unroll
  for (int mi = 0; mi < 4; ++mi)
    #pragma unroll
    for (int nj = 0; nj < 4; ++nj) acc[mi][nj] = (f32x4){0.f,0.f,0.f,0.f};

  // q @ S  (K = 128)
  const s16* Sbase = S + ((size_t)(h*64 + n)*256 + w*64)*128;
  #pragma unroll
  for (int c = 0; c < 4; ++c){
    short8 bf[4];
    #pragma unroll
    for (int nj = 0; nj < 4; ++nj)
      bf[nj] = *(const short8*)(Sbase + (size_t)(nj*16 + lrow)*128 + c*32 + lq*8);
    #pragma unroll
    for (int mi = 0; mi < 4; ++mi)
      #pragma unroll
      for (int nj = 0; nj < 4; ++nj)
        acc[mi][nj] = __builtin_amdgcn_mfma_f32_16x16x32_bf16(qf[mi][c], bf[nj], acc[mi][nj], 0, 0, 0);
  }
  // scale by d_q = b^(row+1)
  #pragma unroll
  for (int mi = 0; mi < 4; ++mi){
    #pragma unroll
    for (int r = 0; r < 4; ++r){
      float dq = exp2f(log2b * (float)(mi*16 + lq*4 + r + 1));
      #pragma unroll
      for (int nj = 0; nj < 4; ++nj) acc[mi][nj][r] *= dq;
    }
  }
  // A @ v  (K = 64)
  #pragma unroll
  for (int c = 0; c < 2; ++c){
    short8 af[4], bf[4];
    #pragma unroll
    for (int mi = 0; mi < 4; ++mi)
      af[mi] = *(short8*)&As[(mi*16 + lrow)*72 + c*32 + lq*8];
    #pragma unroll
    for (int nj = 0; nj < 4; ++nj)
      bf[nj] = *(short8*)&vs[(w*64 + nj*16 + lrow)*72 + c*32 + lq*8];
    #pragma unroll
    for (int mi = 0; mi < 4; ++mi)
      #pragma unroll
      for (int nj = 0; nj < 4; ++nj)
        acc[mi][nj] = __builtin_amdgcn_mfma_f32_16x16x32_bf16(af[mi], bf[nj], acc[mi][nj], 0, 0, 0);
  }
  // write O
  s16* obase = o + (size_t)(n*64)*2048 + h*256;
  #pragma unroll
  for (int mi = 0; mi < 4; ++mi)
    #pragma unroll
    for (int nj = 0; nj < 4; ++nj)
      #pragma unroll
      for (int r = 0; r < 4; ++r){
        int row = mi*16 + lq*4 + r;
        int col = w*64 + nj*16 + lrow;
        obase[(size_t)row*2048 + col] = f2bf(acc[mi][nj][r]);
      }
}

extern "C" void kernel_launch(void* const* d_in, const int* in_sizes, int n_in,
                              void* d_out, int out_size, void* d_ws, size_t ws_size,
                              hipStream_t stream) {
  (void)in_sizes; (void)n_in; (void)out_size; (void)ws_size;
  const float* x     = (const float*)d_in[0];
  const float* ln1_w = (const float*)d_in[1];
  const float* ln1_b = (const float*)d_in[2];
  const float* Wq    = (const float*)d_in[3];
  const float* Wk    = (const float*)d_in[4];
  const float* Wv    = (const float*)d_in[5];
  const float* Wo    = (const float*)d_in[6];
  const float* ln2_w = (const float*)d_in[7];
  const float* ln2_b = (const float*)d_in[8];
  const float* W1    = (const float*)d_in[9];
  const float* b1    = (const float*)d_in[10];
  const float* W2    = (const float*)d_in[11];
  const float* b2    = (const float*)d_in[12];
  float* out = (float*)d_out;
  char* ws = (char*)d_ws;

  // ---- static arena, peak 172 MB (lifetime-aliased) ----
  const size_t MB = 1ull << 20;
  s16* Wqkv_t = (s16*)(ws + 0*MB);   // [0,8)  rows: 0-1023 q, 1024-2047 k, 2048-4095 v
  s16* Wo_t = (s16*)(ws + 8*MB);     // [8,12)
  s16* W1_t = (s16*)(ws + 12*MB);    // [12,20)
  s16* W2_t = (s16*)(ws + 20*MB);    // [20,28)
  s16* hbuf = (s16*)(ws + 28*MB);    // [28,44)  dead after QKV gemm
  s16* h2   = (s16*)(ws + 28*MB);    // [28,44)  alias dead hbuf (post-retention)
  s16* qkv  = (s16*)(ws + 44*MB);    // [44,108) [8192,4096] bf16, dead after ret_attn(b1)
  float* x1 = (float*)(ws + 44*MB);  // [44,76)  alias dead qkv head (post-retention)
  s16* fb   = (s16*)(ws + 76*MB);    // [76,140) alias dead qkv tail + US (FFN acts)
  s16* US   = (s16*)(ws + 108*MB);   // [108,140) bf16 per-batch U->S (in-place scan)
  s16* ob   = (s16*)(ws + 140*MB);   // [140,172)

  // weight transpose-convert (DK^-0.5 folded into Wq)
  conv_t<<<dim3(32,32),  256, 0, stream>>>(Wq, Wqkv_t, 1024, 1024, 0.08838834764831845f);
  conv_t<<<dim3(32,32),  256, 0, stream>>>(Wk, Wqkv_t + (size_t)1024*1024, 1024, 1024, 1.f);
  conv_t<<<dim3(64,32),  256, 0, stream>>>(Wv, Wqkv_t + (size_t)2048*1024, 1024, 2048, 1.f);
  conv_t<<<dim3(32,64),  256, 0, stream>>>(Wo, Wo_t, 2048, 1024, 1.f);
  conv_t<<<dim3(128,32), 256, 0, stream>>>(W1, W1_t, 1024, 4096, 1.f);
  conv_t<<<dim3(32,128), 256, 0, stream>>>(W2, W2_t, 4096, 1024, 1.f);

  ln_bf16<<<8192, 256, 0, stream>>>(x, ln1_w, ln1_b, hbuf);

  // fused QKV: [8192,4096] = hbuf @ Wqkv^T  (256^2 pipelined, 512 blocks)
  gemm256<<<512, 512, 0, stream>>>(hbuf, Wqkv_t, 4096, 1024, qkv, nullptr, 0, 32);

  for (int b = 0; b < 2; ++b){
    const s16* q_b = qkv + (size_t)b*4096*4096;
    const s16* k_b = q_b + 1024;
    const s16* v_b = q_b + 2048;
    s16* ob_b = ob + (size_t)b*4096*2048;
    ret_chunksum<<<512, 256, 0, stream>>>(k_b, v_b, US);
    ret_scan<<<256, 256, 0, stream>>>(US);
    ret_attn<<<512, 256, 0, stream>>>(q_b, k_b, v_b, US, ob_b);
  }

  // Wo: x1 = x + ob @ Wo^T   (256x128 pipelined, 256 blocks, tiles_y=32)
  gemm256h<<<256, 512, 0, stream>>>(ob, Wo_t, 1024, 2048, x1, nullptr, nullptr, x, 0, 32);
  ln_bf16<<<8192, 256, 0, stream>>>(x1, ln2_w, ln2_b, h2);

  // FFN: fb = gelu(h2 @ W1^T + b1)  [8192,4096]  (256^2 pipelined)
  gemm256<<<512, 512, 0, stream>>>(h2, W1_t, 4096, 1024, fb, b1, 1, 32);
  // out = x1 + b2 + fb @ W2^T   (256x128 pipelined, 256 blocks, K=4096)
  gemm256h<<<256, 512, 0, stream>>>(fb, W2_t, 1024, 4096, out, nullptr, b2, x1, 0, 32);
}